// Round 8
// baseline (190.265 us; speedup 1.0000x reference)
//
#include <hip/hip_runtime.h>
#include <stdint.h>

#define N_NODES 100000
#define KNBR 16
#define ALPHA 0.2f
#define SDIM 32          // dims per slice
#define NSLICE 8         // = # XCDs
#define ANODES 64        // nodes per slice-gather block

typedef __attribute__((ext_vector_type(8))) short bf16x8;
typedef __attribute__((ext_vector_type(4))) float f32x4;
typedef __attribute__((ext_vector_type(4))) unsigned int u32x4;
typedef __attribute__((ext_vector_type(2))) unsigned int u32x2;
typedef unsigned short u16;
typedef unsigned int u32;
typedef unsigned char u8;

static __device__ __forceinline__ u16 f2bf(float f) {
  u32 u = __builtin_bit_cast(u32, f);
  u += 0x7fffu + ((u >> 16) & 1u);   // round-to-nearest-even
  return (u16)(u >> 16);
}
static __device__ __forceinline__ float bf2f(u16 s) {
  return __builtin_bit_cast(float, ((u32)s) << 16);
}

// ---- Kernel 1: W -> Wb in MFMA B-fragment order ----
__global__ __launch_bounds__(256) void prep_w_kernel(const float* __restrict__ W,
                                                     u16* __restrict__ Wb) {
  const int t = blockIdx.x * 256 + threadIdx.x;  // 0..8191
  const int l = t & 63;
  const int ct = (t >> 6) & 15;
  const int ks = t >> 10;
  const int colbase = ct * 16 + (l & 15);
  const int k0 = ks * 32 + (l >> 4) * 8;
  u32 wq[4];
#pragma unroll
  for (int q = 0; q < 4; ++q) {
    const u16 b0 = f2bf(W[(k0 + 2 * q) * 256 + colbase]);
    const u16 b1 = f2bf(W[(k0 + 2 * q + 1) * 256 + colbase]);
    wq[q] = (u32)b0 | ((u32)b1 << 16);
  }
  uint4 o = {wq[0], wq[1], wq[2], wq[3]};
  *(uint4*)(Wb + (size_t)t * 8) = o;
}

// ---- Kernel 2: GEMM Y = h @ W + per-row int8 quant. SLICED: slice-major Yq ----
template <bool SLICED>
__global__ __launch_bounds__(256, 4) void gemm_kernel(const float* __restrict__ h,
                                                      const u16* __restrict__ Wb,
                                                      u8* __restrict__ Yq,
                                                      float* __restrict__ scale) {
  __shared__ __align__(16) u16 aS[32 * 256];
  __shared__ float redS[4][32];
  __shared__ float invSS[32];
  const int tid = threadIdx.x;
  const int blk = blockIdx.x;
  const size_t base = (size_t)blk * (32 * 256);

#pragma unroll
  for (int i = 0; i < 8; ++i) {
    const int flat = i * 1024 + tid * 4;
    const int row = flat >> 8, d0 = flat & 255;
    const f32x4 v = __builtin_nontemporal_load((const f32x4*)(h + base + flat));
    uint2 o;
    o.x = (u32)f2bf(v[0]) | ((u32)f2bf(v[1]) << 16);
    o.y = (u32)f2bf(v[2]) | ((u32)f2bf(v[3]) << 16);
    *(uint2*)((char*)aS + row * 512 + ((d0 * 2) ^ ((row & 7) << 4))) = o;
  }
  __syncthreads();

  const int l = tid & 63, wv = tid >> 6;
  const int l15 = l & 15, lg = l >> 4;
  f32x4 acc[2][4] = {};
  const uint4* wbL = ((const uint4*)Wb) + (size_t)(wv * 4) * 64 + l;
  const char* aggB = (const char*)aS;
  const int rb0 = l15 * 512;
  const int xm = (l15 & 7) << 4;
#pragma unroll 2
  for (int ks = 0; ks < 8; ++ks) {
    const int offk = ((ks * 64) + lg * 16) ^ xm;
    const bf16x8 a0 = *(const bf16x8*)(aggB + rb0 + offk);
    const bf16x8 a1 = *(const bf16x8*)(aggB + rb0 + 8192 + offk);
#pragma unroll
    for (int c = 0; c < 4; ++c) {
      const uint4 bw = wbL[ks * 1024 + c * 64];
      const bf16x8 b = __builtin_bit_cast(bf16x8, bw);
      acc[0][c] = __builtin_amdgcn_mfma_f32_16x16x32_bf16(a0, b, acc[0][c], 0, 0, 0);
      acc[1][c] = __builtin_amdgcn_mfma_f32_16x16x32_bf16(a1, b, acc[1][c], 0, 0, 0);
    }
  }

  // rowmax -> scale
#pragma unroll
  for (int rt = 0; rt < 2; ++rt)
#pragma unroll
    for (int j = 0; j < 4; ++j) {
      float m = 0.f;
#pragma unroll
      for (int c = 0; c < 4; ++c) m = fmaxf(m, fabsf(acc[rt][c][j]));
      m = fmaxf(m, __shfl_xor(m, 1)); m = fmaxf(m, __shfl_xor(m, 2));
      m = fmaxf(m, __shfl_xor(m, 4)); m = fmaxf(m, __shfl_xor(m, 8));
      redS[wv][rt * 16 + lg * 4 + j] = m;
    }
  __syncthreads();
  if (tid < 32) {
    float m = fmaxf(fmaxf(redS[0][tid], redS[1][tid]),
                    fmaxf(redS[2][tid], redS[3][tid]));
    m = fmaxf(m, 1e-20f);
    scale[blk * 32 + tid] = m * (1.0f / 127.0f);
    invSS[tid] = 127.0f / m;
  }
  __syncthreads();

  // quantize into LDS u8 tile (XOR-swizzled)
  u8* qS = (u8*)aS;
#pragma unroll
  for (int rt = 0; rt < 2; ++rt)
#pragma unroll
    for (int j = 0; j < 4; ++j) {
      const int r = rt * 16 + lg * 4 + j;
      const float inv = invSS[r];
      const int sw = ((r >> 2) & 7) << 5;
#pragma unroll
      for (int c = 0; c < 4; ++c) {
        float q = rintf(acc[rt][c][j] * inv);
        q = fminf(127.f, fmaxf(-127.f, q));
        qS[r * 256 + ((wv * 64 + c * 16 + l15) ^ sw)] = (u8)((int)q + 128);
      }
    }
  __syncthreads();

  const u32x4* q4 = (const u32x4*)aS;
  if (SLICED) {
    // slice-major: Yq[s][node][32]
#pragma unroll
    for (int rr = 0; rr < 2; ++rr) {
      const int f = rr * 256 + tid;            // 16B piece index in [0,512)
      const int s = f >> 6;
      const int nodeL = (f >> 1) & 31;
      const int half = f & 1;
      const int colx = (s * 32 + half * 16) ^ (((nodeL >> 2) & 7) << 5);
      const u32x4 piece = q4[(nodeL * 256 + colx) >> 4];
      __builtin_nontemporal_store(
          piece, (u32x4*)(Yq + (size_t)s * ((size_t)N_NODES * SDIM) +
                          (size_t)(blk * 32 + nodeL) * SDIM + half * 16));
    }
  } else {
    u32x4* yg = (u32x4*)(Yq + (size_t)blk * 8192);
#pragma unroll
    for (int q = 0; q < 2; ++q) {
      const int f = q * 4096 + tid * 16;
      const int row = f >> 8, col = f & 255;
      const int colx = col ^ (((row >> 2) & 7) << 5);
      __builtin_nontemporal_store(q4[(row * 256 + colx) >> 4], &yg[f >> 4]);
    }
  }
}

// ---- Kernel 3a (sliced): per-XCD L2-resident slice gather ----
// block b: slice = b&7 (-> XCD b%8), 64 nodes; 8 threads per node cover 32 dims.
__global__ __launch_bounds__(256) void slice_gather_kernel(
    const u8* __restrict__ Yq, const float* __restrict__ scale,
    const int* __restrict__ nbr, u16* __restrict__ zws,
    float* __restrict__ ssp) {
  __shared__ int nbrS[ANODES * 17];   // padded stride 17
  const int tid = threadIdx.x;
  const int s = blockIdx.x & 7;
  const int chunk = blockIdx.x >> 3;
  const int nodeBase = chunk * ANODES;

  {  // stage 64x16 indices, coalesced int4
    const int n = tid >> 2, j4 = tid & 3;
    int4 v = {0, 0, 0, 0};
    if (nodeBase + n < N_NODES)
      v = ((const int4*)(nbr + (size_t)nodeBase * KNBR))[tid];
    nbrS[n * 17 + j4 * 4 + 0] = v.x;
    nbrS[n * 17 + j4 * 4 + 1] = v.y;
    nbrS[n * 17 + j4 * 4 + 2] = v.z;
    nbrS[n * 17 + j4 * 4 + 3] = v.w;
  }
  __syncthreads();

  const u8* Ys = Yq + (size_t)s * ((size_t)N_NODES * SDIM);
  const int sub = tid & 7;

#pragma unroll
  for (int p = 0; p < 2; ++p) {
    const int nl = p * 32 + (tid >> 3);
    const int node = nodeBase + nl;
    if (node < N_NODES) {
      int idx[17];
      idx[0] = node;
#pragma unroll
      for (int j = 0; j < 16; ++j) idx[j + 1] = nbrS[nl * 17 + j];

      u32 v[17];
#pragma unroll
      for (int j = 0; j < 17; ++j)
        v[j] = *(const u32*)(Ys + (size_t)idx[j] * SDIM + sub * 4);
      float sj[17];
#pragma unroll
      for (int j = 0; j < 17; ++j) sj[j] = scale[idx[j]];

      float a0 = 0.f, a1 = 0.f, a2 = 0.f, a3 = 0.f, S = 0.f;
#pragma unroll
      for (int j = 0; j < 17; ++j) {
        float f0, f1, f2, f3;
        asm("v_cvt_f32_ubyte0 %0, %1" : "=v"(f0) : "v"(v[j]));
        asm("v_cvt_f32_ubyte1 %0, %1" : "=v"(f1) : "v"(v[j]));
        asm("v_cvt_f32_ubyte2 %0, %1" : "=v"(f2) : "v"(v[j]));
        asm("v_cvt_f32_ubyte3 %0, %1" : "=v"(f3) : "v"(v[j]));
        S += sj[j];
        a0 = fmaf(sj[j], f0, a0);
        a1 = fmaf(sj[j], f1, a1);
        a2 = fmaf(sj[j], f2, a2);
        a3 = fmaf(sj[j], f3, a3);
      }
      const float sc = 1.0f / 17.0f, bias = 128.0f * S;
      a0 = (a0 - bias) * sc; a1 = (a1 - bias) * sc;
      a2 = (a2 - bias) * sc; a3 = (a3 - bias) * sc;
      a0 = (a0 >= 0.f) ? a0 : ALPHA * a0;
      a1 = (a1 >= 0.f) ? a1 : ALPHA * a1;
      a2 = (a2 >= 0.f) ? a2 : ALPHA * a2;
      a3 = (a3 >= 0.f) ? a3 : ALPHA * a3;

      float ss = a0 * a0 + a1 * a1 + a2 * a2 + a3 * a3;
      ss += __shfl_xor(ss, 1); ss += __shfl_xor(ss, 2); ss += __shfl_xor(ss, 4);

      u32x2 o = {(u32)f2bf(a0) | ((u32)f2bf(a1) << 16),
                 (u32)f2bf(a2) | ((u32)f2bf(a3) << 16)};
      __builtin_nontemporal_store(
          o, (u32x2*)(zws + (size_t)node * 256 + s * SDIM + sub * 4));
      if (sub == 0) ssp[node * 8 + s] = ss;
    }
  }
}

// ---- Kernel 3b (sliced): deterministic norm + store ----
__global__ __launch_bounds__(256) void norm_kernel(const u16* __restrict__ zws,
                                                   const float* __restrict__ ssp,
                                                   float* __restrict__ out) {
  const int tid = threadIdx.x;
  const int lane = tid & 63, wv = tid >> 6;
  const int node = __builtin_amdgcn_readfirstlane(blockIdx.x * 4 + wv);

  float f = ssp[node * 8 + (lane & 7)];
  f += __shfl_xor(f, 1); f += __shfl_xor(f, 2); f += __shfl_xor(f, 4);
  const float inv = 1.0f / fmaxf(sqrtf(f), 1e-12f);

  const u32x2 z = *(const u32x2*)(zws + (size_t)node * 256 + lane * 4);
  f32x4 o = {bf2f((u16)(z.x & 0xffff)) * inv, bf2f((u16)(z.x >> 16)) * inv,
             bf2f((u16)(z.y & 0xffff)) * inv, bf2f((u16)(z.y >> 16)) * inv};
  __builtin_nontemporal_store(o, (f32x4*)(out + (size_t)node * 256 + lane * 4));
}

// ---- Kernel 3 (fallback, R5 structure): row-major gather + norm ----
__global__ __launch_bounds__(256) void gather_kernel(const u8* __restrict__ Yq,
                                                     const float* __restrict__ scale,
                                                     const int* __restrict__ nbr,
                                                     float* __restrict__ out) {
  const int tid = threadIdx.x;
  const int lane = tid & 63, wv = tid >> 6;
  const int node = __builtin_amdgcn_readfirstlane(blockIdx.x * 4 + wv);

  const int il = nbr[node * KNBR + (lane & 15)];
  const float vscale = scale[il];
  const float sself = scale[node];
  const u32* yb = (const u32*)Yq;

  u32 v[17];
  v[0] = yb[(size_t)node * 64 + lane];
#pragma unroll
  for (int j = 0; j < 16; ++j) {
    const int r = __builtin_amdgcn_readlane(il, j);
    v[j + 1] = yb[(size_t)r * 64 + lane];
  }

  float a0, a1, a2, a3, S = sself;
  {
    float f0, f1, f2, f3;
    asm("v_cvt_f32_ubyte0 %0, %1" : "=v"(f0) : "v"(v[0]));
    asm("v_cvt_f32_ubyte1 %0, %1" : "=v"(f1) : "v"(v[0]));
    asm("v_cvt_f32_ubyte2 %0, %1" : "=v"(f2) : "v"(v[0]));
    asm("v_cvt_f32_ubyte3 %0, %1" : "=v"(f3) : "v"(v[0]));
    a0 = sself * f0; a1 = sself * f1; a2 = sself * f2; a3 = sself * f3;
  }
#pragma unroll
  for (int j = 0; j < 16; ++j) {
    const float s = __builtin_bit_cast(
        float, __builtin_amdgcn_readlane(__builtin_bit_cast(int, vscale), j));
    float f0, f1, f2, f3;
    asm("v_cvt_f32_ubyte0 %0, %1" : "=v"(f0) : "v"(v[j + 1]));
    asm("v_cvt_f32_ubyte1 %0, %1" : "=v"(f1) : "v"(v[j + 1]));
    asm("v_cvt_f32_ubyte2 %0, %1" : "=v"(f2) : "v"(v[j + 1]));
    asm("v_cvt_f32_ubyte3 %0, %1" : "=v"(f3) : "v"(v[j + 1]));
    S += s;
    a0 = fmaf(s, f0, a0); a1 = fmaf(s, f1, a1);
    a2 = fmaf(s, f2, a2); a3 = fmaf(s, f3, a3);
  }
  const float sc = 1.0f / 17.0f, bias = 128.0f * S;
  a0 = (a0 - bias) * sc; a1 = (a1 - bias) * sc;
  a2 = (a2 - bias) * sc; a3 = (a3 - bias) * sc;
  a0 = (a0 >= 0.f) ? a0 : ALPHA * a0;
  a1 = (a1 >= 0.f) ? a1 : ALPHA * a1;
  a2 = (a2 >= 0.f) ? a2 : ALPHA * a2;
  a3 = (a3 >= 0.f) ? a3 : ALPHA * a3;

  float ss = a0 * a0 + a1 * a1 + a2 * a2 + a3 * a3;
  ss += __shfl_xor(ss, 1);  ss += __shfl_xor(ss, 2);
  ss += __shfl_xor(ss, 4);  ss += __shfl_xor(ss, 8);
  ss += __shfl_xor(ss, 16); ss += __shfl_xor(ss, 32);
  const float inv = 1.0f / fmaxf(sqrtf(ss), 1e-12f);

  f32x4 o = {a0 * inv, a1 * inv, a2 * inv, a3 * inv};
  __builtin_nontemporal_store(o, (f32x4*)(out + (size_t)node * 256 + lane * 4));
}

extern "C" void kernel_launch(void* const* d_in, const int* in_sizes, int n_in,
                              void* d_out, int out_size, void* d_ws, size_t ws_size,
                              hipStream_t stream) {
  const float* h = (const float*)d_in[0];
  const int* nbr = (const int*)d_in[1];
  const float* W = (const float*)d_in[2];
  float* out = (float*)d_out;

  char* ws = (char*)d_ws;
  u16* Wb = (u16*)ws;                                   // 128 KB
  float* scale = (float*)(ws + (1 << 17));              // 400 KB
  u8* Yq = (u8*)(ws + (1 << 20));                       // 25.6 MB
  const size_t offZ = (1 << 20) + (size_t)N_NODES * 256;          // after Yq
  u16* zws = (u16*)(ws + offZ);                         // 51.2 MB bf16 z
  const size_t offSsp = offZ + (size_t)N_NODES * 256 * 2;
  float* ssp = (float*)(ws + offSsp);                   // 3.2 MB partials
  const size_t need = offSsp + (size_t)N_NODES * 8 * 4;

  prep_w_kernel<<<32, 256, 0, stream>>>(W, Wb);
  if (ws_size >= need) {
    gemm_kernel<true><<<N_NODES / 32, 256, 0, stream>>>(h, Wb, Yq, scale);
    const int chunks = (N_NODES + ANODES - 1) / ANODES;   // 1563
    slice_gather_kernel<<<chunks * 8, 256, 0, stream>>>(Yq, scale, nbr, zws, ssp);
    norm_kernel<<<N_NODES / 4, 256, 0, stream>>>(zws, ssp, out);
  } else {
    gemm_kernel<false><<<N_NODES / 32, 256, 0, stream>>>(h, Wb, Yq, scale);
    gather_kernel<<<N_NODES / 4, 256, 0, stream>>>(Yq, scale, nbr, out);
  }
}